// Round 9
// baseline (1264.603 us; speedup 1.0000x reference)
//
#include <hip/hip_runtime.h>
#include <hip/hip_bf16.h>

typedef __hip_bfloat16 bf16;

__device__ __forceinline__ float eluf(float x){ return x > 0.f ? x : (expf(x) - 1.f); }
__device__ __forceinline__ float lrelu02(float x){ return x > 0.f ? x : 0.2f * x; }

// K0: blocks [0, ZB): zero counts+cursor+deg; blocks [ZB, ZB+NBni): per-node noise MLP
__global__ void __launch_bounds__(256) k0_zero_ni(
    unsigned int* __restrict__ zp, size_t zn,
    const float* __restrict__ nf,
    const float* __restrict__ fc1w, const float* __restrict__ fc1b,
    const float* __restrict__ fc2w, const float* __restrict__ fc2b,
    float* __restrict__ ni_arr, int ZB, int N)
{
    int b = (int)blockIdx.x;
    if (b < ZB) {
        size_t i = (size_t)b * blockDim.x + threadIdx.x;
        size_t stride = (size_t)ZB * blockDim.x;
        for (; i < zn; i += stride) zp[i] = 0u;
    } else {
        int n = (b - ZB) * (int)blockDim.x + (int)threadIdx.x;
        if (n >= N) return;
        float f[10];
#pragma unroll
        for (int i = 0; i < 10; i++) f[i] = nf[(size_t)n * 10 + i];
        float ni = fc2b[0];
#pragma unroll
        for (int j = 0; j < 10; j++) {
            float h = fc1b[j];
#pragma unroll
            for (int i = 0; i < 10; i++) h += f[i] * fc1w[j * 10 + i];
            h = eluf(h);
            ni += h * fc2w[j];
        }
        ni_arr[n] = ni;
    }
}

// K12: thread/edge; w from ni[u]+coords; wg_e, counts & deg atomics
__global__ void __launch_bounds__(256) k12_edge(
    const int* __restrict__ ei, const float* __restrict__ coord,
    const float* __restrict__ ni_arr,
    float* __restrict__ wg_e, unsigned int* __restrict__ counts,
    float* __restrict__ deg, int E)
{
    int e = (int)blockIdx.x * (int)blockDim.x + (int)threadIdx.x;
    if (e >= E) return;
    int u = ei[e], v = ei[E + e];
    float2 cu = *(const float2*)(coord + (size_t)u * 2);
    float2 cv = *(const float2*)(coord + (size_t)v * 2);
    float niu = ni_arr[u];
    float dx = cu.x - cv.x, dy = cu.y - cv.y;
    float gw = expf(-(dx * dx + dy * dy) * (1.0f / 1800.0f));
    float x = gw * (1.f + niu);
    float w = 0.1f + 1.9f / (1.f + expf(1.f - x));
    w = (w >= 0.2f) ? w : 0.f;
    wg_e[e] = w;
    if (w > 0.f) {
        atomicAdd(&counts[v], 1u);
        atomicAdd(&deg[v], w);
    }
}

// Kscan_dinv: block 0: single-block exclusive scan; blocks >=1: dinv = rsqrt(deg+1)
__global__ void __launch_bounds__(1024) kscan_dinv(
    const unsigned int* __restrict__ counts, int* __restrict__ offs,
    const float* __restrict__ deg, float* __restrict__ dinv, int N)
{
    if (blockIdx.x != 0) {
        int n = ((int)blockIdx.x - 1) * 1024 + (int)threadIdx.x;
        if (n < N) dinv[n] = rsqrtf(deg[n] + 1.0f);
        return;
    }
    __shared__ int wsum[16];
    int tid = threadIdx.x;
    int lane = tid & 63, wv = tid >> 6;
    int carry = 0;
    for (int base = 0; base < N; base += 4096) {
        int i0 = base + tid * 4;
        uint4 c = make_uint4(0u, 0u, 0u, 0u);
        if (i0 + 3 < N) c = *(const uint4*)(counts + i0);
        else {
            if (i0 + 0 < N) c.x = counts[i0];
            if (i0 + 1 < N) c.y = counts[i0 + 1];
            if (i0 + 2 < N) c.z = counts[i0 + 2];
            if (i0 + 3 < N) c.w = counts[i0 + 3];
        }
        int t0 = (int)c.x, t1 = t0 + (int)c.y, t2 = t1 + (int)c.z, tot = t2 + (int)c.w;
        int incl = tot;
#pragma unroll
        for (int o = 1; o < 64; o <<= 1) {
            int tt = __shfl_up(incl, o, 64);
            if (lane >= o) incl += tt;
        }
        if (lane == 63) wsum[wv] = incl;
        __syncthreads();
        if (wv == 0 && lane < 16) {
            int s2 = wsum[lane];
#pragma unroll
            for (int o = 1; o < 16; o <<= 1) {
                int tt = __shfl_up(s2, o, 16);
                if (lane >= o) s2 += tt;
            }
            wsum[lane] = s2;
        }
        __syncthreads();
        int wpre = (wv > 0) ? wsum[wv - 1] : 0;
        int excl = carry + wpre + (incl - tot);
        int4 o4 = make_int4(excl, excl + t0, excl + t1, excl + t2);
        if (i0 + 3 < N) *(int4*)(offs + i0) = o4;
        else {
            if (i0 + 0 < N) offs[i0]     = o4.x;
            if (i0 + 1 < N) offs[i0 + 1] = o4.y;
            if (i0 + 2 < N) offs[i0 + 2] = o4.z;
            if (i0 + 3 < N) offs[i0 + 3] = o4.w;
        }
        carry += wsum[15];
        __syncthreads();
    }
    if (tid == 0) offs[N] = carry;
}

// K2c: blocks [0,NBe): scatter valid edges into CSR; blocks [NBe,+NBn): node projections
__global__ void __launch_bounds__(256) k2c_scatter_proj(
    const int* __restrict__ ei, const float* __restrict__ wg_e,
    const int* __restrict__ offs, unsigned int* __restrict__ cursor,
    int2* __restrict__ csr,
    const float* __restrict__ x_local, const float* __restrict__ x_global,
    const float* __restrict__ gat_w, const float* __restrict__ gcn_w,
    const float* __restrict__ att_src, const float* __restrict__ att_dst,
    bf16* __restrict__ xp, float* __restrict__ asv, float* __restrict__ adv,
    int NBe, int N, int E)
{
    int b = (int)blockIdx.x;
    if (b < NBe) {
        int e = b * (int)blockDim.x + (int)threadIdx.x;
        if (e >= E) return;
        float w = wg_e[e];
        if (w <= 0.f) return;
        int u = ei[e], v = ei[E + e];
        int pos = offs[v] + (int)atomicAdd(&cursor[v], 1u);
        int2 val;
        val.x = u;
        val.y = __float_as_int(w);
        csr[pos] = val;
    } else {
        int n = ((b - NBe) * (int)blockDim.x + (int)threadIdx.x) >> 6;
        int lane = threadIdx.x & 63;
        if (n >= N) return;
        float xl = x_local[(size_t)n * 64 + lane];
        float xg = x_global[(size_t)n * 64 + lane];
        float accA = 0.f, accG = 0.f;
        const float* wA = gat_w + lane * 64;
        const float* wG = gcn_w + lane * 64;
#pragma unroll 8
        for (int k = 0; k < 64; k++) {
            float xlk = __shfl(xl, k, 64);
            float xgk = __shfl(xg, k, 64);
            accA += xlk * wA[k];
            accG += xgk * wG[k];
        }
        xp[(size_t)n * 128 + lane]      = __float2bfloat16(accA);
        xp[(size_t)n * 128 + 64 + lane] = __float2bfloat16(accG);
        float va = accA * att_src[lane];
        float vd = accA * att_dst[lane];
#pragma unroll
        for (int o = 32; o; o >>= 1) {
            va += __shfl_xor(va, o, 64);
            vd += __shfl_xor(vd, o, 64);
        }
        if (lane == 0) { asv[n] = va; adv[n] = vd; }
    }
}

// K3: wave per dst node. Plain exp (no max-subtraction; logits bounded),
// per-lane denom accumulation, one reduce at the end.
__global__ void __launch_bounds__(256) k3_gather(
    const int* __restrict__ offs, const int2* __restrict__ csr,
    const float* __restrict__ asv, const float* __restrict__ adv,
    const float* __restrict__ dinv, const bf16* __restrict__ xp,
    const float* __restrict__ gat_b, const float* __restrict__ gcn_b,
    const float* __restrict__ fw1, const float* __restrict__ fb1,
    const float* __restrict__ fw2, const float* __restrict__ fb2,
    float* __restrict__ out, int N)
{
    __shared__ float cat_lds[4][128];
    int wv = threadIdx.x >> 6;
    int lane = threadIdx.x & 63;
    int v = blockIdx.x * 4 + wv;
    if (v >= N) return;

    int t = lane & 15;        // 16B-slot within row (t<8: GAT chans, t>=8: GCN)
    int g = lane >> 4;        // edge group 0..3
    bool isA = t < 8;
    int beg = offs[v], end = offs[v + 1];
    float adv_v = adv[v];
    float dinv_v = dinv[v];
    float p_l = expf(lrelu02(asv[v] + adv_v));   // self-loop exp weight
    float s_lane = 0.f;
    float acc[8];
#pragma unroll
    for (int k = 0; k < 8; k++) acc[k] = 0.f;

    for (int base = beg; base < end; base += 64) {
        int i = base + lane;
        bool has = i < end;
        int2 ew = has ? csr[i] : make_int2(0, 0);
        int u = ew.x;
        float w = __int_as_float(ew.y);
        float p = 0.f, nrm = 0.f;
        if (has) {
            p = expf(lrelu02(asv[u] + adv_v));
            nrm = dinv[u] * w * dinv_v;
        }
        s_lane += p;

        int cnt = end - base; if (cnt > 64) cnt = 64;
        int steps = (cnt + 3) >> 2;
#pragma unroll 2
        for (int st = 0; st < steps; st++) {
            int idx = st * 4 + g;
            float pj = __shfl(p, idx, 64);
            float nj = __shfl(nrm, idx, 64);
            int   uj = __shfl(u, idx, 64);
            float scale = isA ? pj : nj;
            uint4 d = *(const uint4*)(xp + (size_t)uj * 128 + t * 8);
            unsigned du0 = d.x, du1 = d.y, du2 = d.z, du3 = d.w;
            acc[0] += scale * __uint_as_float(du0 << 16);
            acc[1] += scale * __uint_as_float(du0 & 0xffff0000u);
            acc[2] += scale * __uint_as_float(du1 << 16);
            acc[3] += scale * __uint_as_float(du1 & 0xffff0000u);
            acc[4] += scale * __uint_as_float(du2 << 16);
            acc[5] += scale * __uint_as_float(du2 & 0xffff0000u);
            acc[6] += scale * __uint_as_float(du3 << 16);
            acc[7] += scale * __uint_as_float(du3 & 0xffff0000u);
        }
    }
    // reduce denom + the 4 edge-groups
#pragma unroll
    for (int o = 32; o; o >>= 1) s_lane += __shfl_xor(s_lane, o, 64);
#pragma unroll
    for (int k = 0; k < 8; k++) {
        acc[k] += __shfl_xor(acc[k], 16, 64);
        acc[k] += __shfl_xor(acc[k], 32, 64);
    }
    float s = s_lane + p_l;
    // self-loop contribution
    {
        uint4 d = *(const uint4*)(xp + (size_t)v * 128 + t * 8);
        float sl = isA ? p_l : (dinv_v * dinv_v);
        unsigned du0 = d.x, du1 = d.y, du2 = d.z, du3 = d.w;
        acc[0] += sl * __uint_as_float(du0 << 16);
        acc[1] += sl * __uint_as_float(du0 & 0xffff0000u);
        acc[2] += sl * __uint_as_float(du1 << 16);
        acc[3] += sl * __uint_as_float(du1 & 0xffff0000u);
        acc[4] += sl * __uint_as_float(du2 << 16);
        acc[5] += sl * __uint_as_float(du2 & 0xffff0000u);
        acc[6] += sl * __uint_as_float(du3 << 16);
        acc[7] += sl * __uint_as_float(du3 & 0xffff0000u);
    }
    // epilogue
    float inv_s = 1.f / (s + 1e-16f);
    int cbase = t * 8;
#pragma unroll
    for (int k = 0; k < 8; k++) {
        float x;
        if (isA) x = eluf(acc[k] * inv_s + gat_b[cbase + k]);
        else { float c = acc[k] + gcn_b[cbase - 64 + k]; x = c > 0.f ? c : 0.f; }
        acc[k] = x;
    }
    if (g == 0) {
        float4* op = (float4*)(out + (size_t)N + (size_t)v * 128 + cbase);
        op[0] = make_float4(acc[0], acc[1], acc[2], acc[3]);
        op[1] = make_float4(acc[4], acc[5], acc[6], acc[7]);
        float4* lp = (float4*)(&cat_lds[wv][cbase]);
        lp[0] = make_float4(acc[0], acc[1], acc[2], acc[3]);
        lp[1] = make_float4(acc[4], acc[5], acc[6], acc[7]);
    }
    // fuse MLP
    float accf = fb1[lane];
    const float4* wrow = (const float4*)(fw1 + lane * 128);
    const float4* cl = (const float4*)cat_lds[wv];
#pragma unroll 8
    for (int k = 0; k < 32; k++) {
        float4 cv = cl[k];
        float4 w4 = wrow[k];
        accf += cv.x * w4.x + cv.y * w4.y + cv.z * w4.z + cv.w * w4.w;
    }
    float hf = accf > 0.f ? accf : 0.f;
    float p2 = hf * fw2[lane];
#pragma unroll
    for (int o = 32; o; o >>= 1) p2 += __shfl_xor(p2, o, 64);
    if (lane == 0) out[v] = p2 + fb2[0];
}

extern "C" void kernel_launch(void* const* d_in, const int* in_sizes, int n_in,
                              void* d_out, int out_size, void* d_ws, size_t ws_size,
                              hipStream_t stream) {
    const float* x_local  = (const float*)d_in[0];
    const float* x_global = (const float*)d_in[1];
    const float* noise_f  = (const float*)d_in[2];
    const float* coord    = (const float*)d_in[3];
    const int*   ei       = (const int*)d_in[4];
    const float* fc1_w    = (const float*)d_in[5];
    const float* fc1_b    = (const float*)d_in[6];
    const float* fc2_w    = (const float*)d_in[7];
    const float* fc2_b    = (const float*)d_in[8];
    const float* gat_w    = (const float*)d_in[9];
    const float* gat_b    = (const float*)d_in[10];
    const float* att_src  = (const float*)d_in[11];
    const float* att_dst  = (const float*)d_in[12];
    const float* gcn_w    = (const float*)d_in[13];
    const float* gcn_b    = (const float*)d_in[14];
    const float* fuse_w1  = (const float*)d_in[15];
    const float* fuse_b1  = (const float*)d_in[16];
    const float* fuse_w2  = (const float*)d_in[17];
    const float* fuse_b2  = (const float*)d_in[18];
    float* out = (float*)d_out;

    const int N = out_size / 129;        // pred [N] + cat [N,128]
    const int E = in_sizes[4] / 2;

    auto rup = [](size_t b) { return (b + 255) & ~(size_t)255; };
    char* p = (char*)d_ws;
    auto carve = [&](size_t bytes) { char* q = p; p += rup(bytes); return (void*)q; };

    // counts + cursor + deg contiguous -> zeroed in one pass
    unsigned int* counts = (unsigned int*)carve((size_t)N * 4);
    unsigned int* cursor = (unsigned int*)carve((size_t)N * 4);
    float* deg   = (float*)carve((size_t)N * 4);
    float* dinv  = (float*)carve((size_t)N * 4);
    int*   offs  = (int*)  carve(((size_t)N + 1) * 4);
    float* asv   = (float*)carve((size_t)N * 4);
    float* adv   = (float*)carve((size_t)N * 4);
    float* ni    = (float*)carve((size_t)N * 4);
    float* wg_e  = (float*)carve((size_t)E * 4);
    int2*  csr   = (int2*) carve((size_t)E * 8);
    bf16*  xp    = (bf16*) carve((size_t)N * 128 * 2);

    dim3 blk(256);
    int NBn  = (N + 3) / 4;              // wave-per-node blocks
    int NBni = (N + 255) / 256;          // thread-per-node blocks
    int NBe  = (E + 255) / 256;          // thread-per-edge blocks
    int ZB   = 256;                      // zeroing blocks in k0

    k0_zero_ni<<<ZB + NBni, blk, 0, stream>>>(counts, (rup((size_t)N * 4) * 3) / 4,
        noise_f, fc1_w, fc1_b, fc2_w, fc2_b, ni, ZB, N);

    k12_edge<<<NBe, blk, 0, stream>>>(ei, coord, ni, wg_e, counts, deg, E);

    kscan_dinv<<<1 + (N + 1023) / 1024, 1024, 0, stream>>>(counts, offs, deg, dinv, N);

    k2c_scatter_proj<<<NBe + NBn, blk, 0, stream>>>(ei, wg_e, offs, cursor, csr,
        x_local, x_global, gat_w, gcn_w, att_src, att_dst, xp, asv, adv,
        NBe, N, E);

    k3_gather<<<NBn, blk, 0, stream>>>(offs, csr, asv, adv, dinv, xp,
        gat_b, gcn_b, fuse_w1, fuse_b1, fuse_w2, fuse_b2, out, N);
}